// Round 5
// baseline (278.386 us; speedup 1.0000x reference)
//
#include <hip/hip_runtime.h>

#define N 1681
#define BS 32
#define THREADS 256
#define NROWS_TOTAL (BS * N)            // 53792
#define MAXC ((BS * N * N) / 4)         // 22606088 float4 chunks per input
#define NBLK (BS * 41 * 2)              // 2624 pass1 blocks (half-band each)
#define PARTS_PER_MAT 82                // 2 partials per band * 41 bands

// ws layout: bsums[128] f64 | dpart[NBLK*N] f32 | sp[53792] f32 | st[53792] f32

typedef __attribute__((address_space(1))) const void* gas_ptr;
typedef __attribute__((address_space(3))) void* las_ptr;

__device__ __forceinline__ void async16(const float4* g, const float4* l) {
  __builtin_amdgcn_global_load_lds((gas_ptr)g, (las_ptr)l, 16, 0, 0);
}

union SM {
  float4 stage[4][2][2][448];  // [wave][buf][pred/targ][chunk]  = 112 KiB
  float dsum[N];               // overlays stage after main loop
};

__global__ __launch_bounds__(THREADS) void pass1_kernel(
    const float* __restrict__ pred,
    const float* __restrict__ targ,
    float* __restrict__ sp,
    float* __restrict__ st,
    float* __restrict__ dpart) {
  __shared__ SM sm;
  __shared__ float spl[21], stl[21];

  const int b    = blockIdx.x;          // 0..2623
  const int tid  = threadIdx.x;
  const int lane = tid & 63;
  const int wid  = tid >> 6;
  const int band = b >> 1;
  const int halfsel = b & 1;
  const int Rbase = band * 41 + halfsel * 21;  // first global row of this block
  const int nr    = halfsel ? 20 : 21;
  const int h     = wid;                        // row alignment class: rows R with (R&3)==h
  const int rr0   = (h - (Rbase & 3)) & 3;
  const int nrw   = (nr - rr0 + 3) >> 2;        // rows for this wave (5 or 6)

  const float4* __restrict__ pred4 = (const float4*)pred;
  const float4* __restrict__ targ4 = (const float4*)targ;

  float dprod[7][4];
#pragma unroll
  for (int t2 = 0; t2 < 7; ++t2)
#pragma unroll
    for (int ee = 0; ee < 4; ++ee) dprod[t2][ee] = 0.0f;

  // stage one full row (421 chunks, padded to 448) of pred+targ into this
  // wave's private LDS buffer: 14 global_load_lds, no VGPR destinations.
#define ISSUE(BUF, Q) do {                                               \
    _Pragma("unroll")                                                    \
    for (int t2_ = 0; t2_ < 7; ++t2_) {                                  \
      const int c_ = min((Q) + t2_ * 64 + lane, MAXC - 1);               \
      async16(pred4 + c_, &sm.stage[wid][BUF][0][t2_ * 64]);             \
      async16(targ4 + c_, &sm.stage[wid][BUF][1][t2_ * 64]);             \
    }                                                                    \
  } while (0)

#define COMPUTE(BUF, RIDX) do {                                          \
    float psq = 0.0f, tsq = 0.0f;                                        \
    _Pragma("unroll")                                                    \
    for (int t2_ = 0; t2_ < 7; ++t2_) {                                  \
      const float4 p4 = sm.stage[wid][BUF][0][t2_ * 64 + lane];          \
      const float4 t4 = sm.stage[wid][BUF][1][t2_ * 64 + lane];          \
      const float pv[4] = {p4.x, p4.y, p4.z, p4.w};                      \
      const float tv[4] = {t4.x, t4.y, t4.z, t4.w};                      \
      if (t2_ == 0 || t2_ == 6) {                                        \
        const int colb = t2_ * 256 + 4 * lane - h;                       \
        _Pragma("unroll")                                                \
        for (int ee = 0; ee < 4; ++ee) {                                 \
          const bool ok = (unsigned)(colb + ee) < (unsigned)N;           \
          const float pm = ok ? pv[ee] : 0.0f;                           \
          const float tm = ok ? tv[ee] : 0.0f;                           \
          psq = fmaf(pm, pm, psq);                                       \
          tsq = fmaf(tm, tm, tsq);                                       \
          dprod[t2_][ee] = fmaf(pm, tm, dprod[t2_][ee]);                 \
        }                                                                \
      } else {                                                           \
        _Pragma("unroll")                                                \
        for (int ee = 0; ee < 4; ++ee) {                                 \
          psq = fmaf(pv[ee], pv[ee], psq);                               \
          tsq = fmaf(tv[ee], tv[ee], tsq);                               \
          dprod[t2_][ee] = fmaf(pv[ee], tv[ee], dprod[t2_][ee]);         \
        }                                                                \
      }                                                                  \
    }                                                                    \
    _Pragma("unroll")                                                    \
    for (int off = 32; off > 0; off >>= 1) {                             \
      psq += __shfl_down(psq, off, 64);                                  \
      tsq += __shfl_down(tsq, off, 64);                                  \
    }                                                                    \
    if (lane == 0) { spl[RIDX] = psq; stl[RIDX] = tsq; }                 \
  } while (0)

  // wave-private double-buffered pipeline; no block barriers in the loop.
  int R   = Rbase + rr0;
  int q   = (R * N) >> 2;   // R*N <= 90.4M < 2^31
  int rem = nrw;
  int buf = 0;
  ISSUE(0, q);
  while (rem > 0) {
    const bool more = (rem > 1);
    if (more) {
      ISSUE(buf ^ 1, q + 1681);   // next row of this class: +4 rows = +1681 chunks
      asm volatile("s_waitcnt vmcnt(14)" ::: "memory");  // wait current buf only
    } else {
      asm volatile("s_waitcnt vmcnt(0)" ::: "memory");
    }
    COMPUTE(buf, R - Rbase);
    buf ^= 1; R += 4; q += 1681; --rem;
  }

  // staging buffers dead for all waves after this barrier -> overlay dsum
  __syncthreads();
  for (int idx = tid; idx < N; idx += THREADS) sm.dsum[idx] = 0.0f;
  __syncthreads();
#pragma unroll
  for (int t2 = 0; t2 < 7; ++t2)
#pragma unroll
    for (int ee = 0; ee < 4; ++ee) {
      const int col = t2 * 256 + 4 * lane + ee - h;
      if ((unsigned)col < (unsigned)N) atomicAdd(&sm.dsum[col], dprod[t2][ee]);
    }
  __syncthreads();
  for (int idx = tid; idx < N; idx += THREADS)
    dpart[(size_t)b * N + idx] = sm.dsum[idx];
  if (tid < nr) {
    sp[Rbase + tid] = spl[tid];
    st[Rbase + tid] = stl[tid];
  }
}

__global__ __launch_bounds__(THREADS) void fin1_kernel(
    const float* __restrict__ sp,
    const float* __restrict__ st,
    const float* __restrict__ dpart,
    double* __restrict__ bsums) {
  __shared__ double red[4];

  double acc = 0.0;
  for (int g = blockIdx.x * THREADS + threadIdx.x; g < NROWS_TOTAL;
       g += gridDim.x * THREADS) {
    const int l = g / N;
    const int j = g - l * N;
    const float* __restrict__ dp = dpart + (size_t)l * PARTS_PER_MAT * N + j;
    float dv = 0.0f;
    for (int p = 0; p < PARTS_PER_MAT; ++p) dv += dp[(size_t)p * N];
    const double s = (double)sp[g] * (double)st[g];
    acc += (double)dv / sqrt(s);
  }
#pragma unroll
  for (int off = 32; off > 0; off >>= 1) acc += __shfl_down(acc, off, 64);
  const int wid = threadIdx.x >> 6;
  if ((threadIdx.x & 63) == 0) red[wid] = acc;
  __syncthreads();
  if (threadIdx.x == 0)
    bsums[blockIdx.x] = red[0] + red[1] + red[2] + red[3];
}

__global__ __launch_bounds__(64) void fin2_kernel(
    const double* __restrict__ bsums, float* __restrict__ out) {
  double acc = bsums[threadIdx.x] + bsums[threadIdx.x + 64];
#pragma unroll
  for (int off = 32; off > 0; off >>= 1) acc += __shfl_down(acc, off, 64);
  if (threadIdx.x == 0)
    out[0] = (float)(-acc / ((double)BS * (double)N));
}

extern "C" void kernel_launch(void* const* d_in, const int* in_sizes, int n_in,
                              void* d_out, int out_size, void* d_ws, size_t ws_size,
                              hipStream_t stream) {
  const float* pred = (const float*)d_in[0];
  const float* targ = (const float*)d_in[1];

  double* bsums = (double*)d_ws;                          // 128 doubles (8B-aligned at base)
  float*  dpart = (float*)(bsums + 128);                  // NBLK*N floats (~17.6 MB)
  float*  sp    = dpart + (size_t)NBLK * N;               // 53792 floats
  float*  st    = sp + (size_t)NROWS_TOTAL;               // 53792 floats

  pass1_kernel<<<NBLK, THREADS, 0, stream>>>(pred, targ, sp, st, dpart);
  fin1_kernel<<<128, THREADS, 0, stream>>>(sp, st, dpart, bsums);
  fin2_kernel<<<1, 64, 0, stream>>>(bsums, (float*)d_out);
}